// Round 13
// baseline (594.720 us; speedup 1.0000x reference)
//
#include <hip/hip_runtime.h>

#define PI_F 3.14159265358979323846f

constexpr int GRIDN = 512;
constexpr int BOXN  = 256;
constexpr int NPTS  = 30000;
constexpr int NCLS  = 2;
constexpr int NLAT  = 16;
constexpr int HDIM  = 256;
constexpr int LFREQ = 10;
constexpr int BATCH = 4;
constexpr int NROWS = BATCH*NPTS;     // 120000
constexpr int RM    = 48;             // rows per block (2500 blocks; 52KB LDS -> 3 blocks/CU)

// scaling: A-words x 2^11, B-words x 2^14, accumulator scale 2^25
#define ASC   2048.0f
#define AINV  (1.0f/2048.0f)
#define OINV  (1.0f/33554432.0f)
#define BSC   16384.0f

typedef _Float16 f16x8 __attribute__((ext_vector_type(8)));
typedef float    f32x4 __attribute__((ext_vector_type(4)));

__device__ __forceinline__ float elu_f(float x){ return x > 0.f ? x : (__expf(x) - 1.0f); }

// split scaled value vs into hi/lo f16 bit-patterns (lo = exact residual, same scale)
__device__ __forceinline__ void split_f16(float vs, uint32_t& hb, uint32_t& lb){
    const _Float16 h = (_Float16)vs;
    const _Float16 l = (_Float16)(vs - (float)h);
    union { _Float16 f; uint16_t u; } uh, ul;
    uh.f = h; ul.f = l;
    hb = uh.u; lb = ul.u;
}
// pack activation: scale by 2^11, split, pack hi(low16)|lo(high16)  [proven path]
__device__ __forceinline__ uint32_t pack_act(float v){
    uint32_t hb, lb;
    split_f16(v * ASC, hb, lb);
    return hb | (lb << 16);
}
__device__ __forceinline__ float unpack_act(uint32_t u){
    union { uint16_t u16; _Float16 f; } a, b;
    a.u16 = (uint16_t)(u & 0xffffu);
    b.u16 = (uint16_t)(u >> 16);
    return ((float)a.f + (float)b.f) * AINV;
}

// K'-doubled B prepack: per layer, windows of 16 orig-k (32 K'), per (window,n16):
// B'1 (dup bh) 1KB + B'3 (dup bl) 1KB.  lay0: 6 windows (K=96); lay1..6: 16 windows.
__host__ __device__ __forceinline__ size_t wp_off(int lay){
    return (lay == 0) ? 0 : (size_t)(6*16*2048 + (size_t)(lay-1)*16*16*2048);
}

// -------- prepack weights: B'1[p]=dup16(f16_hi(W[16wi+4g+p][c])), B'3[p]=dup16(f16_lo) --------
__global__ void prepack_kernel(const float* __restrict__ Win,
                               const float* __restrict__ Wlay,
                               unsigned char* __restrict__ wp)
{
    const int tid = blockIdx.x*256 + threadIdx.x;
    if (tid >= 102*16*64) return;     // 102 windows total (6 + 6*16)
    const int lane = tid & 63;
    const int n16  = (tid >> 6) & 15;
    const int widx = tid >> 10;       // 0..101
    int lay, wi;
    if (widx < 6) { lay = 0; wi = widx; }
    else          { lay = 1 + (widx-6)/16; wi = (widx-6) & 15; }
    const int g = lane >> 4;
    const int c = 16*n16 + (lane & 15);
    uint32_t b1[4], b3[4];
    #pragma unroll
    for (int p = 0; p < 4; ++p) {
        const int kap = 16*wi + 4*g + p;   // original-k index
        float w = 0.f;
        if (lay == 0) { if (kap < 76) w = Win[kap*HDIM + c]; }
        else w = Wlay[(size_t)(lay-1)*HDIM*HDIM + (size_t)kap*HDIM + c];
        uint32_t hb, lb;
        split_f16(w * BSC, hb, lb);
        b1[p] = hb | (hb << 16);      // (bh, bh) at k' = even, odd
        b3[p] = lb | (lb << 16);      // (bl, bl)
    }
    uint4* dst = (uint4*)(wp + wp_off(lay)) + (size_t)(wi*16 + n16)*128 + lane;
    dst[0]  = make_uint4(b1[0], b1[1], b1[2], b1[3]);   // B'1 slot
    dst[64] = make_uint4(b3[0], b3[1], b3[2], b3[3]);   // B'3 slot (+1KB)
}

// -------------------- fused MLP on matrix cores (K'-doubled, 4 MFMA, zero A-repack) ----------
// 8 waves, n8-split; A-fragment = raw uint4 from LDS (stored hi|lo word IS the K'-fragment).
// D = sum A'*B'1 + sum A'*B'3 = (ah+al)(bh+bl) exactly.
__launch_bounds__(512, 4)
__global__ void mlp_fused(const float* __restrict__ pos,
                          const float* __restrict__ zlat,
                          const unsigned char* __restrict__ wp,
                          const float* __restrict__ Wout1,
                          const float* __restrict__ Wout2,
                          const float* __restrict__ orient,
                          float* __restrict__ out_fp,
                          float* __restrict__ out_disp,
                          float2* __restrict__ proj)
{
    __shared__ uint4 h4[RM*64];      // 48 KB: packed hi/lo activations, XOR-swizzled
    __shared__ float w1s[HDIM*3];
    uint32_t* hs = (uint32_t*)h4;
    const int t = threadIdx.x;
    const int lane = t & 63;
    const int wv = t >> 6;           // 0..7
    const int row0 = blockIdx.x * RM;
    const int g  = lane >> 4;
    const int rb = lane & 15;

    // feat: 48 rows x 96 cols (60 posenc + 16 z + 20 zero pad); 48*96 = 4608 = 9*512
    for (int idx = t; idx < RM*96; idx += 512) {
        const int r = idx / 96, c = idx - r*96;
        const int row = row0 + r;
        const int b = row / NPTS, n = row - b*NPTS;
        float v = 0.f;
        if (c < 60) {
            const int d = c / 20, rem = c - d*20;
            const int f = (rem < 10) ? rem : rem - 10;
            const float ang = pos[n*3+d] * (float)(1<<f) * PI_F;
            v = (rem < 10) ? sinf(ang) : cosf(ang);
        } else if (c < 76) {
            v = zlat[b*NLAT + (c - 60)];
        }
        hs[r*256 + (c ^ ((r&7)<<2))] = pack_act(v);
    }
    for (int idx = t; idx < HDIM*3; idx += 512) w1s[idx] = Wout1[idx];
    __syncthreads();

    for (int lay = 0; lay < 7; ++lay) {
        const int KS = lay ? 8 : 3;
        const uint4* bp = (const uint4*)(wp + wp_off(lay));

        f32x4 acc[6];
        #pragma unroll
        for (int i = 0; i < 6; ++i) { f32x4 zz = {0.f,0.f,0.f,0.f}; acc[i] = zz; }

        uint4 B1A[2][2], B3A[2][2], B1B[2][2], B3B[2][2];   // [window-in-step][nn]

        auto LOADB = [&](uint4 (&B1)[2][2], uint4 (&B3)[2][2], int k){
            #pragma unroll
            for (int w = 0; w < 2; ++w) {
                const int wi = 2*k + w;
                #pragma unroll
                for (int nn = 0; nn < 2; ++nn) {
                    const size_t s0 = (size_t)(wi*16 + 2*wv + nn)*128 + lane;
                    B1[w][nn] = bp[s0];
                    B3[w][nn] = bp[s0 + 64];
                }
            }
        };
        auto STEP = [&](const uint4 (&B1)[2][2], const uint4 (&B3)[2][2], int k){
            #pragma unroll
            for (int m = 0; m < 3; ++m) {
                const int r = 16*m + rb;
                const int s = r & 7;
                #pragma unroll
                for (int w = 0; w < 2; ++w) {
                    union { uint4 q; f16x8 v; } A;
                    A.q = h4[r*64 + ((8*k + 4*w + g) ^ s)];   // raw fragment, no repack
                    #pragma unroll
                    for (int nn = 0; nn < 2; ++nn) {
                        union { uint4 q; f16x8 v; } c1, c3;
                        c1.q = B1[w][nn]; c3.q = B3[w][nn];
                        f32x4 a = acc[m*2+nn];
                        a = __builtin_amdgcn_mfma_f32_16x16x32_f16(A.v, c1.v, a, 0, 0, 0);
                        a = __builtin_amdgcn_mfma_f32_16x16x32_f16(A.v, c3.v, a, 0, 0, 0);
                        acc[m*2+nn] = a;
                    }
                }
            }
        };

        LOADB(B1A, B3A, 0);
        for (int k = 0; k < KS; k += 2) {
            if (k+1 < KS) LOADB(B1B, B3B, k+1);
            STEP(B1A, B3A, k);
            if (k+1 < KS) {
                if (k+2 < KS) LOADB(B1A, B3A, k+2);
                STEP(B1B, B3B, k+1);
            }
        }

        __syncthreads();   // all h reads of this layer done
        const bool do_elu = (lay >= 1);
        #pragma unroll
        for (int m = 0; m < 3; ++m) {
            #pragma unroll
            for (int nn = 0; nn < 2; ++nn) {
                #pragma unroll
                for (int j = 0; j < 4; ++j) {
                    float v = acc[m*2+nn][j] * OINV;       // descale 2^-25
                    if (do_elu) v = elu_f(v);
                    const int r = 16*m + 4*g + j;          // C/D: row = 4*(lane>>4)+reg
                    const int c = 32*wv + 16*nn + rb;      // C/D: col = lane&15
                    hs[r*256 + (c ^ ((r&7)<<2))] = pack_act(v);
                }
            }
        }
        __syncthreads();
    }

    // ---- head: 256->3 (elu) -> 3x3, rotate, project ----
    if (t < RM) {
        const int row = row0 + t;
        const int b = row / NPTS, n = row - b*NPTS;
        const int s = (t & 7) << 2;
        float o0=0.f, o1=0.f, o2=0.f;
        for (int k = 0; k < HDIM; ++k) {
            const float hv = unpack_act(hs[t*256 + (k ^ s)]);
            o0 = fmaf(hv, w1s[k*3+0], o0);
            o1 = fmaf(hv, w1s[k*3+1], o1);
            o2 = fmaf(hv, w1s[k*3+2], o2);
        }
        o0 = elu_f(o0); o1 = elu_f(o1); o2 = elu_f(o2);
        const float d0 = o0*Wout2[0] + o1*Wout2[3] + o2*Wout2[6];
        const float d1 = o0*Wout2[1] + o1*Wout2[4] + o2*Wout2[7];
        const float d2 = o0*Wout2[2] + o1*Wout2[5] + o2*Wout2[8];
        const float p0 = pos[n*3+0] + d0;
        const float p1 = pos[n*3+1] + d1;
        const float p2 = pos[n*3+2] + d2;
        out_disp[(size_t)row*3+0] = d0; out_disp[(size_t)row*3+1] = d1; out_disp[(size_t)row*3+2] = d2;
        out_fp[(size_t)row*3+0]   = p0; out_fp[(size_t)row*3+1]   = p1; out_fp[(size_t)row*3+2]   = p2;
        float sa,ca,sb,cb,sc,cc;
        sincosf(orient[b*3+0], &sa, &ca);
        sincosf(orient[b*3+1], &sb, &cb);
        sincosf(orient[b*3+2], &sc, &cc);
        const float R00 =  ca*cb*cc - sa*sc;
        const float R10 =  sa*cb*cc + ca*sc;
        const float R20 = -sb*cc;
        const float R01 = -ca*cb*sc - sa*cc;
        const float R11 = -sa*cb*sc + ca*cc;
        const float R21 =  sb*sc;
        float2 pr;
        pr.x = p0*R00 + p1*R10 + p2*R20;
        pr.y = p0*R01 + p1*R11 + p2*R21;
        proj[row] = pr;
    }
}

// ---------------- bilinear scatter with per-point class softmax ----------------
__global__ void scatter_kernel(const float2* __restrict__ proj,
                               const float* __restrict__ amp,
                               const float* __restrict__ ampvar,
                               float* __restrict__ img)
{
    const int i = blockIdx.x * 256 + threadIdx.x;
    if (i >= NROWS) return;
    const int b = i / NPTS;
    const int n = i - b*NPTS;
    const float2 pr = proj[i];
    float x = (pr.x + 0.5f) * (float)(GRIDN-1);
    float y = (pr.y + 0.5f) * (float)(GRIDN-1);
    x = fminf(fmaxf(x, 0.f), 511.0f);
    y = fminf(fmaxf(y, 0.f), 511.0f);
    const float x0f = floorf(x), y0f = floorf(y);
    const float fx = x - x0f, fy = y - y0f;
    const int x0 = (int)x0f, y0 = (int)y0f;
    const int x1 = min(x0+1, GRIDN-1), y1 = min(y0+1, GRIDN-1);
    const float av0 = ampvar[n], av1 = ampvar[NPTS + n];
    const float m  = fmaxf(av0, av1);
    const float e0 = __expf(av0 - m), e1 = __expf(av1 - m);
    const float inv = 1.0f / (e0 + e1);
    const float w0 = amp[n]        * e0 * inv;
    const float w1 = amp[NPTS + n] * e1 * inv;
    const float w00 = (1.f-fx)*(1.f-fy), w10 = fx*(1.f-fy), w01 = (1.f-fx)*fy, w11 = fx*fy;
    float* img0 = img + (size_t)(b*NCLS + 0)*GRIDN*GRIDN;
    float* img1 = img + (size_t)(b*NCLS + 1)*GRIDN*GRIDN;
    const int i00 = y0*GRIDN + x0, i10 = y0*GRIDN + x1;
    const int i01 = y1*GRIDN + x0, i11 = y1*GRIDN + x1;
    atomicAdd(img0 + i00, w0*w00); atomicAdd(img0 + i10, w0*w10);
    atomicAdd(img0 + i01, w0*w01); atomicAdd(img0 + i11, w0*w11);
    atomicAdd(img1 + i00, w1*w00); atomicAdd(img1 + i10, w1*w10);
    atomicAdd(img1 + i01, w1*w01); atomicAdd(img1 + i11, w1*w11);
}

// ---------------- generic 1-row-per-block radix-2 FFT pass ----------------
template<int N, bool INV, bool RIN, bool ROUT>
__global__ void fft_pass(const float* __restrict__ in, float* __restrict__ out,
                         int in_per, long in_s1, long in_s2, long in_es,
                         int out_per, long out_s1, long out_s2, long out_es,
                         float scale)
{
    __shared__ float2 s[N];
    const int t  = threadIdx.x;            // N/2 threads
    const int rb = blockIdx.x;
    const long ib = (long)(rb / in_per) * in_s1 + (long)(rb % in_per) * in_s2;
    constexpr int LOG2N = (N == 512) ? 9 : 8;
    #pragma unroll
    for (int j = 0; j < 2; ++j) {
        const int i  = t + j*(N/2);
        const int ri = (int)(__brev((unsigned)i) >> (32 - LOG2N));
        float2 v;
        if (RIN) { v.x = in[ib + (long)i*in_es]; v.y = 0.f; }
        else       v = ((const float2*)in)[ib + (long)i*in_es];
        s[ri] = v;
    }
    for (int len = 1; len < N; len <<= 1) {
        __syncthreads();
        const int p  = t & (len-1);
        const int i0 = ((t & ~(len-1)) << 1) | p;
        const float ang = (INV ? PI_F : -PI_F) * (float)p / (float)len;
        float sn, cs; __sincosf(ang, &sn, &cs);   // |ang| <= pi: HW fast path is safe
        const float2 a  = s[i0];
        const float2 bv = s[i0 + len];
        const float2 bt = make_float2(bv.x*cs - bv.y*sn, bv.x*sn + bv.y*cs);
        s[i0]       = make_float2(a.x + bt.x, a.y + bt.y);
        s[i0 + len] = make_float2(a.x - bt.x, a.y - bt.y);
    }
    __syncthreads();
    const long ob = (long)(rb / out_per) * out_s1 + (long)(rb % out_per) * out_s2;
    #pragma unroll
    for (int j = 0; j < 2; ++j) {
        const int i = t + j*(N/2);
        if (ROUT) out[ob + (long)i*out_es] = s[i].x * scale;
        else {
            float2 v = s[i]; v.x *= scale; v.y *= scale;
            ((float2*)out)[ob + (long)i*out_es] = v;
        }
    }
}

// -------- filter + sum over classes + crop + Hermitian part + shift phase --------
__global__ void combine_kernel(const float2* __restrict__ F,
                               const float* __restrict__ Afac,
                               const float* __restrict__ Bw,
                               const float* __restrict__ shift,
                               float2* __restrict__ Q)
{
    const int u = blockIdx.x;
    const int b = blockIdx.y;
    const int v = threadIdx.x;
    const int mu  = (u < 128) ? u : u + 256;
    const int mv  = (v < 128) ? v : v + 256;
    const int u2  = (256 - u) & 255;
    const int v2  = (256 - v) & 255;
    const int mu2 = (u2 < 128) ? u2 : u2 + 256;
    const int mv2 = (v2 < 128) ? v2 : v2 + 256;
    const float fy1 = (float)((mu  < 256) ? mu  : mu  - 512) / 512.0f;
    const float fx1 = (float)((mv  < 256) ? mv  : mv  - 512) / 512.0f;
    const float fy2 = (float)((mu2 < 256) ? mu2 : mu2 - 512) / 512.0f;
    const float fx2 = (float)((mv2 < 256) ? mv2 : mv2 - 512) / 512.0f;
    const float R1 = fy1*fy1 + fx1*fx1;
    const float R2 = fy2*fy2 + fx2*fx2;
    float a1x=0.f, a1y=0.f, a2x=0.f, a2y=0.f;
    #pragma unroll
    for (int c = 0; c < NCLS; ++c) {
        const float bw = Bw[c];
        const float f1 = Afac[c] * __expf(-bw*bw*R1);
        const float f2 = Afac[c] * __expf(-bw*bw*R2);
        const float2* Fi = F + ((size_t)(b*NCLS + c) << 18);
        const float2 v1 = Fi[mu *512 + mv ];
        const float2 vh = Fi[mu2*512 + mv2];
        a1x = fmaf(f1, v1.x, a1x); a1y = fmaf(f1, v1.y, a1y);
        a2x = fmaf(f2, vh.x, a2x); a2y = fmaf(f2, vh.y, a2y);
    }
    const float Gx = 0.5f*(a1x + a2x);
    const float Gy = 0.5f*(a1y - a2y);
    const float fu = (float)((u < 128) ? u : u - 256) / 256.0f;
    const float fv = (float)((v < 128) ? v : v - 256) / 256.0f;
    const float th = -2.0f*PI_F*(shift[b*2+0]*fv + shift[b*2+1]*fu);
    float sn, cs; __sincosf(th, &sn, &cs);
    float2 o;
    o.x = Gx*cs - Gy*sn;
    o.y = Gx*sn + Gy*cs;
    Q[((size_t)b << 16) + (size_t)u*256 + v] = o;
}

extern "C" void kernel_launch(void* const* d_in, const int* in_sizes, int n_in,
                              void* d_out, int out_size, void* d_ws, size_t ws_size,
                              hipStream_t stream)
{
    (void)in_sizes; (void)n_in; (void)out_size; (void)ws_size;
    const float* z      = (const float*)d_in[0];
    const float* orient = (const float*)d_in[1];
    const float* shift  = (const float*)d_in[2];
    const float* pos    = (const float*)d_in[3];
    const float* amp    = (const float*)d_in[4];
    const float* ampvar = (const float*)d_in[5];
    const float* Win    = (const float*)d_in[6];
    const float* Wlay   = (const float*)d_in[7];
    const float* Wout1  = (const float*)d_in[8];
    const float* Wout2  = (const float*)d_in[9];
    const float* Afac   = (const float*)d_in[10];
    const float* Bw     = (const float*)d_in[11];

    float* out      = (float*)d_out;
    float* out_img  = out;
    float* out_fp   = out + (size_t)BATCH*BOXN*BOXN;
    float* out_disp = out_fp + (size_t)NROWS*3;

    char*   ws   = (char*)d_ws;
    float*  img  = (float*)ws;                               // 8 MB
    float2* bufA = (float2*)(ws + (size_t)8*1024*1024);      // 16 MB (overlaps prepack)
    unsigned char* wp = (unsigned char*)(ws + (size_t)8*1024*1024);  // 3.34 MB, dead after mlp
    float2* Q    = (float2*)(ws + (size_t)25165824);         // 2 MB
    float2* proj = (float2*)(ws + (size_t)27262976);         // 960 KB

    (void)hipMemsetAsync(img, 0, (size_t)BATCH*NCLS*GRIDN*GRIDN*sizeof(float), stream);

    prepack_kernel<<<(102*16*64 + 255)/256, 256, 0, stream>>>(Win, Wlay, wp);

    mlp_fused<<<NROWS/RM, 512, 0, stream>>>(pos, z, wp, Wout1, Wout2, orient,
                                            out_fp, out_disp, proj);
    scatter_kernel<<<(NROWS+255)/256, 256, 0, stream>>>(proj, amp, ampvar, img);

    fft_pass<512,false,true ,false><<<BATCH*NCLS*512, 256, 0, stream>>>(
        img, (float*)bufA, 512, 262144, 512, 1, 512, 262144, 512, 1, 1.0f);
    fft_pass<512,false,false,false><<<BATCH*NCLS*512, 256, 0, stream>>>(
        (const float*)bufA, (float*)bufA, 512, 262144, 1, 512, 512, 262144, 1, 512, 1.0f);

    combine_kernel<<<dim3(256, BATCH), 256, 0, stream>>>(bufA, Afac, Bw, shift, Q);

    fft_pass<256,true ,false,false><<<BATCH*256, 128, 0, stream>>>(
        (const float*)Q, (float*)Q, 256, 65536, 256, 1, 256, 65536, 256, 1, 1.0f/256.0f);
    fft_pass<256,true ,false,true ><<<BATCH*256, 128, 0, stream>>>(
        (const float*)Q, out_img, 256, 65536, 1, 256, 256, 65536, 1, 256, 0.25f/256.0f);
}

// Round 14
// 482.744 us; speedup vs baseline: 1.2320x; 1.2320x over previous
//
#include <hip/hip_runtime.h>

#define PI_F 3.14159265358979323846f

constexpr int GRIDN = 512;
constexpr int BOXN  = 256;
constexpr int NPTS  = 30000;
constexpr int NCLS  = 2;
constexpr int NLAT  = 16;
constexpr int HDIM  = 256;
constexpr int LFREQ = 10;
constexpr int BATCH = 4;
constexpr int NROWS = BATCH*NPTS;     // 120000
constexpr int RM    = 48;             // rows per block (2500 blocks; 52KB LDS -> 3 blocks/CU)

// scaling: A-words x 2^11, B-words x 2^14, accumulator scale 2^25
#define ASC   2048.0f
#define AINV  (1.0f/2048.0f)
#define OINV  (1.0f/33554432.0f)
#define BSC   16384.0f

typedef _Float16 f16x8 __attribute__((ext_vector_type(8)));
typedef float    f32x4 __attribute__((ext_vector_type(4)));

__device__ __forceinline__ float elu_f(float x){ return x > 0.f ? x : (__expf(x) - 1.0f); }

// split scaled value vs into hi/lo f16 bit-patterns (lo = exact residual, same scale)
__device__ __forceinline__ void split_f16(float vs, uint32_t& hb, uint32_t& lb){
    const _Float16 h = (_Float16)vs;
    const _Float16 l = (_Float16)(vs - (float)h);
    union { _Float16 f; uint16_t u; } uh, ul;
    uh.f = h; ul.f = l;
    hb = uh.u; lb = ul.u;
}
// pack activation: scale by 2^11, split, pack hi(low16)|lo(high16)
__device__ __forceinline__ uint32_t pack_act(float v){
    uint32_t hb, lb;
    split_f16(v * ASC, hb, lb);
    return hb | (lb << 16);
}
__device__ __forceinline__ float unpack_act(uint32_t u){
    union { uint16_t u16; _Float16 f; } a, b;
    a.u16 = (uint16_t)(u & 0xffffu);
    b.u16 = (uint16_t)(u >> 16);
    return ((float)a.f + (float)b.f) * AINV;
}

// prepack byte offsets: lay0 = 3 ksteps, lay1..6 = 8 ksteps; per (kstep,n16): hi 1KB + lo 1KB
__host__ __device__ __forceinline__ size_t wp_off(int lay){
    return (lay == 0) ? 0 : (size_t)(98304 + (lay-1)*262144);
}

// -------- prepack weights into MFMA B-fragment order, scaled split-f16 hi/lo --------
__global__ void prepack_kernel(const float* __restrict__ Win,
                               const float* __restrict__ Wlay,
                               unsigned char* __restrict__ wp)
{
    const int tid = blockIdx.x*256 + threadIdx.x;
    if (tid >= 7*8*16*64) return;
    const int lane  = tid & 63;
    const int n16   = (tid >> 6) & 15;
    const int kstep = (tid >> 10) & 7;
    const int lay   = tid >> 13;
    if (lay == 0 && kstep >= 3) return;
    const int kbase = 32*kstep + 8*(lane >> 4);
    const int c = 16*n16 + (lane & 15);
    uint32_t hw[4], lw[4];
    #pragma unroll
    for (int p = 0; p < 4; ++p) {
        uint32_t hh0=0, hh1=0, ll0=0, ll1=0;
        #pragma unroll
        for (int q = 0; q < 2; ++q) {
            const int k = kbase + 2*p + q;
            float w = 0.f;
            if (lay == 0) { if (k < 76) w = Win[k*HDIM + c]; }
            else w = Wlay[(size_t)(lay-1)*HDIM*HDIM + (size_t)k*HDIM + c];
            uint32_t hb, lb;
            split_f16(w * BSC, hb, lb);
            if (q == 0) { hh0 = hb; ll0 = lb; } else { hh1 = hb; ll1 = lb; }
        }
        hw[p] = hh0 | (hh1 << 16);
        lw[p] = ll0 | (ll1 << 16);
    }
    uint4* dst = (uint4*)(wp + wp_off(lay)) + (size_t)((kstep*16 + n16)*2)*64 + lane;
    dst[0]  = make_uint4(hw[0], hw[1], hw[2], hw[3]);   // hi slot
    dst[64] = make_uint4(lw[0], lw[1], lw[2], lw[3]);   // lo slot (+1KB)
}

// -------------------- fused MLP on matrix cores (scaled split-f16, 3 MFMA) --------------------
// 8 waves: each wave owns 2 n16-groups (32 cols) x all 48 rows.  [r12 proven version - FROZEN]
__launch_bounds__(512, 4)
__global__ void mlp_fused(const float* __restrict__ pos,
                          const float* __restrict__ zlat,
                          const unsigned char* __restrict__ wp,
                          const float* __restrict__ Wout1,
                          const float* __restrict__ Wout2,
                          const float* __restrict__ orient,
                          float* __restrict__ out_fp,
                          float* __restrict__ out_disp,
                          float2* __restrict__ proj)
{
    __shared__ uint4 h4[RM*64];      // 48 KB: packed hi/lo activations, XOR-swizzled
    __shared__ float w1s[HDIM*3];
    uint32_t* hs = (uint32_t*)h4;
    const int t = threadIdx.x;
    const int lane = t & 63;
    const int wv = t >> 6;           // 0..7
    const int row0 = blockIdx.x * RM;
    const int g  = lane >> 4;
    const int rb = lane & 15;

    // feat: 48 rows x 96 cols (60 posenc + 16 z + 20 zero pad); 48*96 = 4608 = 9*512
    for (int idx = t; idx < RM*96; idx += 512) {
        const int r = idx / 96, c = idx - r*96;
        const int row = row0 + r;
        const int b = row / NPTS, n = row - b*NPTS;
        float v = 0.f;
        if (c < 60) {
            const int d = c / 20, rem = c - d*20;
            const int f = (rem < 10) ? rem : rem - 10;
            const float ang = pos[n*3+d] * (float)(1<<f) * PI_F;
            v = (rem < 10) ? sinf(ang) : cosf(ang);
        } else if (c < 76) {
            v = zlat[b*NLAT + (c - 60)];
        }
        hs[r*256 + (c ^ ((r&7)<<2))] = pack_act(v);
    }
    for (int idx = t; idx < HDIM*3; idx += 512) w1s[idx] = Wout1[idx];
    __syncthreads();

    for (int lay = 0; lay < 7; ++lay) {
        const int KS = lay ? 8 : 3;
        const uint4* bp = (const uint4*)(wp + wp_off(lay));

        f32x4 acc[6];
        #pragma unroll
        for (int i = 0; i < 6; ++i) { f32x4 zz = {0.f,0.f,0.f,0.f}; acc[i] = zz; }

        uint4 BH0[2], BL0[2], BH1[2], BL1[2];

        auto LOADB = [&](uint4 (&H)[2], uint4 (&L)[2], int k){
            #pragma unroll
            for (int f = 0; f < 2; ++f) {
                const size_t s0 = (size_t)((k*16 + 2*wv + f)*2)*64 + lane;
                H[f] = bp[s0];
                L[f] = bp[s0 + 64];
            }
        };
        auto STEP = [&](const uint4 (&H)[2], const uint4 (&L)[2], int k){
            #pragma unroll
            for (int m = 0; m < 3; ++m) {
                const int r = 16*m + rb;
                const int s = r & 7;
                const int G0 = 8*k + 2*g;
                const uint4 p0 = h4[r*64 + (G0 ^ s)];
                const uint4 p1 = h4[r*64 + ((G0+1) ^ s)];
                const uint32_t e0=p0.x, e1=p0.y, e2=p0.z, e3=p0.w;
                const uint32_t e4=p1.x, e5=p1.y, e6=p1.z, e7=p1.w;
                union { uint4 q; f16x8 v; } ah, al;
                ah.q = make_uint4((e0 & 0xffffu) | (e1 << 16),
                                  (e2 & 0xffffu) | (e3 << 16),
                                  (e4 & 0xffffu) | (e5 << 16),
                                  (e6 & 0xffffu) | (e7 << 16));
                al.q = make_uint4((e0 >> 16) | (e1 & 0xffff0000u),
                                  (e2 >> 16) | (e3 & 0xffff0000u),
                                  (e4 >> 16) | (e5 & 0xffff0000u),
                                  (e6 >> 16) | (e7 & 0xffff0000u));
                #pragma unroll
                for (int nn = 0; nn < 2; ++nn) {
                    union { uint4 q; f16x8 v; } bh, bl;
                    bh.q = H[nn]; bl.q = L[nn];
                    f32x4 a = acc[m*2+nn];
                    a = __builtin_amdgcn_mfma_f32_16x16x32_f16(ah.v, bl.v, a, 0, 0, 0);
                    a = __builtin_amdgcn_mfma_f32_16x16x32_f16(al.v, bh.v, a, 0, 0, 0);
                    a = __builtin_amdgcn_mfma_f32_16x16x32_f16(ah.v, bh.v, a, 0, 0, 0);
                    acc[m*2+nn] = a;
                }
            }
        };

        LOADB(BH0, BL0, 0);
        for (int k = 0; k < KS; k += 2) {
            if (k+1 < KS) LOADB(BH1, BL1, k+1);
            STEP(BH0, BL0, k);
            if (k+1 < KS) {
                if (k+2 < KS) LOADB(BH0, BL0, k+2);
                STEP(BH1, BL1, k+1);
            }
        }

        __syncthreads();   // all h reads of this layer done
        const bool do_elu = (lay >= 1);
        #pragma unroll
        for (int m = 0; m < 3; ++m) {
            #pragma unroll
            for (int nn = 0; nn < 2; ++nn) {
                #pragma unroll
                for (int j = 0; j < 4; ++j) {
                    float v = acc[m*2+nn][j] * OINV;       // descale 2^-25
                    if (do_elu) v = elu_f(v);
                    const int r = 16*m + 4*g + j;          // C/D: row = 4*(lane>>4)+reg
                    const int c = 32*wv + 16*nn + rb;      // C/D: col = lane&15
                    hs[r*256 + (c ^ ((r&7)<<2))] = pack_act(v);
                }
            }
        }
        __syncthreads();
    }

    // ---- head: 256->3 (elu) -> 3x3, rotate, project ----
    if (t < RM) {
        const int row = row0 + t;
        const int b = row / NPTS, n = row - b*NPTS;
        const int s = (t & 7) << 2;
        float o0=0.f, o1=0.f, o2=0.f;
        for (int k = 0; k < HDIM; ++k) {
            const float hv = unpack_act(hs[t*256 + (k ^ s)]);
            o0 = fmaf(hv, w1s[k*3+0], o0);
            o1 = fmaf(hv, w1s[k*3+1], o1);
            o2 = fmaf(hv, w1s[k*3+2], o2);
        }
        o0 = elu_f(o0); o1 = elu_f(o1); o2 = elu_f(o2);
        const float d0 = o0*Wout2[0] + o1*Wout2[3] + o2*Wout2[6];
        const float d1 = o0*Wout2[1] + o1*Wout2[4] + o2*Wout2[7];
        const float d2 = o0*Wout2[2] + o1*Wout2[5] + o2*Wout2[8];
        const float p0 = pos[n*3+0] + d0;
        const float p1 = pos[n*3+1] + d1;
        const float p2 = pos[n*3+2] + d2;
        out_disp[(size_t)row*3+0] = d0; out_disp[(size_t)row*3+1] = d1; out_disp[(size_t)row*3+2] = d2;
        out_fp[(size_t)row*3+0]   = p0; out_fp[(size_t)row*3+1]   = p1; out_fp[(size_t)row*3+2]   = p2;
        float sa,ca,sb,cb,sc,cc;
        sincosf(orient[b*3+0], &sa, &ca);
        sincosf(orient[b*3+1], &sb, &cb);
        sincosf(orient[b*3+2], &sc, &cc);
        const float R00 =  ca*cb*cc - sa*sc;
        const float R10 =  sa*cb*cc + ca*sc;
        const float R20 = -sb*cc;
        const float R01 = -ca*cb*sc - sa*cc;
        const float R11 = -sa*cb*sc + ca*cc;
        const float R21 =  sb*sc;
        float2 pr;
        pr.x = p0*R00 + p1*R10 + p2*R20;
        pr.y = p0*R01 + p1*R11 + p2*R21;
        proj[row] = pr;
    }
}

// ---------------- bilinear scatter with per-point class softmax ----------------
__global__ void scatter_kernel(const float2* __restrict__ proj,
                               const float* __restrict__ amp,
                               const float* __restrict__ ampvar,
                               float* __restrict__ img)
{
    const int i = blockIdx.x * 256 + threadIdx.x;
    if (i >= NROWS) return;
    const int b = i / NPTS;
    const int n = i - b*NPTS;
    const float2 pr = proj[i];
    float x = (pr.x + 0.5f) * (float)(GRIDN-1);
    float y = (pr.y + 0.5f) * (float)(GRIDN-1);
    x = fminf(fmaxf(x, 0.f), 511.0f);
    y = fminf(fmaxf(y, 0.f), 511.0f);
    const float x0f = floorf(x), y0f = floorf(y);
    const float fx = x - x0f, fy = y - y0f;
    const int x0 = (int)x0f, y0 = (int)y0f;
    const int x1 = min(x0+1, GRIDN-1), y1 = min(y0+1, GRIDN-1);
    const float av0 = ampvar[n], av1 = ampvar[NPTS + n];
    const float m  = fmaxf(av0, av1);
    const float e0 = __expf(av0 - m), e1 = __expf(av1 - m);
    const float inv = 1.0f / (e0 + e1);
    const float w0 = amp[n]        * e0 * inv;
    const float w1 = amp[NPTS + n] * e1 * inv;
    const float w00 = (1.f-fx)*(1.f-fy), w10 = fx*(1.f-fy), w01 = (1.f-fx)*fy, w11 = fx*fy;
    float* img0 = img + (size_t)(b*NCLS + 0)*GRIDN*GRIDN;
    float* img1 = img + (size_t)(b*NCLS + 1)*GRIDN*GRIDN;
    const int i00 = y0*GRIDN + x0, i10 = y0*GRIDN + x1;
    const int i01 = y1*GRIDN + x0, i11 = y1*GRIDN + x1;
    atomicAdd(img0 + i00, w0*w00); atomicAdd(img0 + i10, w0*w10);
    atomicAdd(img0 + i01, w0*w01); atomicAdd(img0 + i11, w0*w11);
    atomicAdd(img1 + i00, w1*w00); atomicAdd(img1 + i10, w1*w10);
    atomicAdd(img1 + i01, w1*w01); atomicAdd(img1 + i11, w1*w11);
}

// ---- row-pass FFT512 packing the two REAL class images as re/im of one complex FFT ----
__global__ void fft_row_pair(const float* __restrict__ img, float2* __restrict__ Z)
{
    __shared__ float2 s[512];
    const int t  = threadIdx.x;           // 256
    const int rb = blockIdx.x;            // b*512 + y
    const int b  = rb >> 9, y = rb & 511;
    const float* p0 = img + ((size_t)(b*2+0) << 18) + (size_t)y*512;
    const float* p1 = img + ((size_t)(b*2+1) << 18) + (size_t)y*512;
    #pragma unroll
    for (int j = 0; j < 2; ++j) {
        const int i  = t + j*256;
        const int ri = (int)(__brev((unsigned)i) >> 23);
        s[ri] = make_float2(p0[i], p1[i]);
    }
    for (int len = 1; len < 512; len <<= 1) {
        __syncthreads();
        const int p  = t & (len-1);
        const int i0 = ((t & ~(len-1)) << 1) | p;
        const float ang = -PI_F * (float)p / (float)len;
        float sn, cs; __sincosf(ang, &sn, &cs);
        const float2 a  = s[i0];
        const float2 bv = s[i0 + len];
        const float2 bt = make_float2(bv.x*cs - bv.y*sn, bv.x*sn + bv.y*cs);
        s[i0]       = make_float2(a.x + bt.x, a.y + bt.y);
        s[i0 + len] = make_float2(a.x - bt.x, a.y - bt.y);
    }
    __syncthreads();
    float2* zo = Z + ((size_t)b << 18) + (size_t)y*512;
    #pragma unroll
    for (int j = 0; j < 2; ++j) {
        const int i = t + j*256;
        zo[i] = s[i];
    }
}

// ---------------- generic 1-row-per-block radix-2 FFT pass ----------------
template<int N, bool INV, bool RIN, bool ROUT>
__global__ void fft_pass(const float* __restrict__ in, float* __restrict__ out,
                         int in_per, long in_s1, long in_s2, long in_es,
                         int out_per, long out_s1, long out_s2, long out_es,
                         float scale)
{
    __shared__ float2 s[N];
    const int t  = threadIdx.x;            // N/2 threads
    const int rb = blockIdx.x;
    const long ib = (long)(rb / in_per) * in_s1 + (long)(rb % in_per) * in_s2;
    constexpr int LOG2N = (N == 512) ? 9 : 8;
    #pragma unroll
    for (int j = 0; j < 2; ++j) {
        const int i  = t + j*(N/2);
        const int ri = (int)(__brev((unsigned)i) >> (32 - LOG2N));
        float2 v;
        if (RIN) { v.x = in[ib + (long)i*in_es]; v.y = 0.f; }
        else       v = ((const float2*)in)[ib + (long)i*in_es];
        s[ri] = v;
    }
    for (int len = 1; len < N; len <<= 1) {
        __syncthreads();
        const int p  = t & (len-1);
        const int i0 = ((t & ~(len-1)) << 1) | p;
        const float ang = (INV ? PI_F : -PI_F) * (float)p / (float)len;
        float sn, cs; __sincosf(ang, &sn, &cs);   // |ang| <= pi: HW fast path is safe
        const float2 a  = s[i0];
        const float2 bv = s[i0 + len];
        const float2 bt = make_float2(bv.x*cs - bv.y*sn, bv.x*sn + bv.y*cs);
        s[i0]       = make_float2(a.x + bt.x, a.y + bt.y);
        s[i0 + len] = make_float2(a.x - bt.x, a.y - bt.y);
    }
    __syncthreads();
    const long ob = (long)(rb / out_per) * out_s1 + (long)(rb % out_per) * out_s2;
    #pragma unroll
    for (int j = 0; j < 2; ++j) {
        const int i = t + j*(N/2);
        if (ROUT) out[ob + (long)i*out_es] = s[i].x * scale;
        else {
            float2 v = s[i]; v.x *= scale; v.y *= scale;
            ((float2*)out)[ob + (long)i*out_es] = v;
        }
    }
}

// -------- unpack packed real-pair spectrum + filter + class-sum + crop + Herm + shift --------
// Z = FFT2(img_c0 + i*img_c1) per batch.  F0(k) = (Z(k)+conj(Z(-k)))/2,
// F1(k) = -i(Z(k)-conj(Z(-k)))/2.  Crop-mirror positions handled with explicit indices.
__global__ void combine_kernel(const float2* __restrict__ Z,
                               const float* __restrict__ Afac,
                               const float* __restrict__ Bw,
                               const float* __restrict__ shift,
                               float2* __restrict__ Q)
{
    const int u = blockIdx.x;
    const int b = blockIdx.y;
    const int v = threadIdx.x;
    const int mu  = (u < 128) ? u : u + 256;
    const int mv  = (v < 128) ? v : v + 256;
    const int u2  = (256 - u) & 255;
    const int v2  = (256 - v) & 255;
    const int mu2 = (u2 < 128) ? u2 : u2 + 256;
    const int mv2 = (v2 < 128) ? v2 : v2 + 256;
    const int nmu  = (512 - mu)  & 511;   // true 512-mirrors for unpacking
    const int nmv  = (512 - mv)  & 511;
    const int nmu2 = (512 - mu2) & 511;
    const int nmv2 = (512 - mv2) & 511;

    const float2* Zb = Z + ((size_t)b << 18);
    const float2 A   = Zb[(size_t)mu  *512 + mv ];
    const float2 Am  = Zb[(size_t)nmu *512 + nmv];
    const float2 A2  = Zb[(size_t)mu2 *512 + mv2];
    const float2 A2m = Zb[(size_t)nmu2*512 + nmv2];

    float2 F1v[2], FHv[2];
    F1v[0] = make_float2(0.5f*(A.x + Am.x),  0.5f*(A.y - Am.y));     // F0(k)
    F1v[1] = make_float2(0.5f*(A.y + Am.y), -0.5f*(A.x - Am.x));     // F1(k)
    FHv[0] = make_float2(0.5f*(A2.x + A2m.x),  0.5f*(A2.y - A2m.y)); // F0(crop-mirror)
    FHv[1] = make_float2(0.5f*(A2.y + A2m.y), -0.5f*(A2.x - A2m.x)); // F1(crop-mirror)

    const float fy1 = (float)((mu  < 256) ? mu  : mu  - 512) / 512.0f;
    const float fx1 = (float)((mv  < 256) ? mv  : mv  - 512) / 512.0f;
    const float fy2 = (float)((mu2 < 256) ? mu2 : mu2 - 512) / 512.0f;
    const float fx2 = (float)((mv2 < 256) ? mv2 : mv2 - 512) / 512.0f;
    const float R1 = fy1*fy1 + fx1*fx1;
    const float R2 = fy2*fy2 + fx2*fx2;
    float a1x=0.f, a1y=0.f, a2x=0.f, a2y=0.f;
    #pragma unroll
    for (int c = 0; c < NCLS; ++c) {
        const float bw = Bw[c];
        const float f1 = Afac[c] * __expf(-bw*bw*R1);
        const float f2 = Afac[c] * __expf(-bw*bw*R2);
        a1x = fmaf(f1, F1v[c].x, a1x); a1y = fmaf(f1, F1v[c].y, a1y);
        a2x = fmaf(f2, FHv[c].x, a2x); a2y = fmaf(f2, FHv[c].y, a2y);
    }
    const float Gx = 0.5f*(a1x + a2x);
    const float Gy = 0.5f*(a1y - a2y);
    const float fu = (float)((u < 128) ? u : u - 256) / 256.0f;
    const float fv = (float)((v < 128) ? v : v - 256) / 256.0f;
    const float th = -2.0f*PI_F*(shift[b*2+0]*fv + shift[b*2+1]*fu);
    float sn, cs; __sincosf(th, &sn, &cs);
    float2 o;
    o.x = Gx*cs - Gy*sn;
    o.y = Gx*sn + Gy*cs;
    Q[((size_t)b << 16) + (size_t)u*256 + v] = o;
}

extern "C" void kernel_launch(void* const* d_in, const int* in_sizes, int n_in,
                              void* d_out, int out_size, void* d_ws, size_t ws_size,
                              hipStream_t stream)
{
    (void)in_sizes; (void)n_in; (void)out_size; (void)ws_size;
    const float* z      = (const float*)d_in[0];
    const float* orient = (const float*)d_in[1];
    const float* shift  = (const float*)d_in[2];
    const float* pos    = (const float*)d_in[3];
    const float* amp    = (const float*)d_in[4];
    const float* ampvar = (const float*)d_in[5];
    const float* Win    = (const float*)d_in[6];
    const float* Wlay   = (const float*)d_in[7];
    const float* Wout1  = (const float*)d_in[8];
    const float* Wout2  = (const float*)d_in[9];
    const float* Afac   = (const float*)d_in[10];
    const float* Bw     = (const float*)d_in[11];

    float* out      = (float*)d_out;
    float* out_img  = out;
    float* out_fp   = out + (size_t)BATCH*BOXN*BOXN;
    float* out_disp = out_fp + (size_t)NROWS*3;

    char*   ws   = (char*)d_ws;
    float*  img  = (float*)ws;                               // 8 MB: [b][c][512][512] real
    float2* Zb   = (float2*)(ws + (size_t)8*1024*1024);      // 8 MB: [b][512][512] complex (packed pair)
    unsigned char* wp = (unsigned char*)(ws + (size_t)8*1024*1024);  // 1.63 MB, dead after mlp (Z written later)
    float2* Q    = (float2*)(ws + (size_t)25165824);         // 2 MB
    float2* proj = (float2*)(ws + (size_t)27262976);         // 960 KB

    (void)hipMemsetAsync(img, 0, (size_t)BATCH*NCLS*GRIDN*GRIDN*sizeof(float), stream);

    prepack_kernel<<<(7*8*16*64 + 255)/256, 256, 0, stream>>>(Win, Wlay, wp);

    mlp_fused<<<NROWS/RM, 512, 0, stream>>>(pos, z, wp, Wout1, Wout2, orient,
                                            out_fp, out_disp, proj);
    scatter_kernel<<<(NROWS+255)/256, 256, 0, stream>>>(proj, amp, ampvar, img);

    // packed forward FFT2: rows (real pair -> complex), then columns (in place)
    fft_row_pair<<<BATCH*512, 256, 0, stream>>>(img, Zb);
    fft_pass<512,false,false,false><<<BATCH*512, 256, 0, stream>>>(
        (const float*)Zb, (float*)Zb, 512, 262144, 1, 512, 512, 262144, 1, 512, 1.0f);

    combine_kernel<<<dim3(256, BATCH), 256, 0, stream>>>(Zb, Afac, Bw, shift, Q);

    fft_pass<256,true ,false,false><<<BATCH*256, 128, 0, stream>>>(
        (const float*)Q, (float*)Q, 256, 65536, 256, 1, 256, 65536, 256, 1, 1.0f/256.0f);
    fft_pass<256,true ,false,true ><<<BATCH*256, 128, 0, stream>>>(
        (const float*)Q, out_img, 256, 65536, 1, 256, 256, 65536, 1, 256, 0.25f/256.0f);
}

// Round 15
// 426.391 us; speedup vs baseline: 1.3948x; 1.1322x over previous
//
#include <hip/hip_runtime.h>

#define PI_F 3.14159265358979323846f

constexpr int GRIDN = 512;
constexpr int BOXN  = 256;
constexpr int NPTS  = 30000;
constexpr int NCLS  = 2;
constexpr int NLAT  = 16;
constexpr int HDIM  = 256;
constexpr int LFREQ = 10;
constexpr int BATCH = 4;
constexpr int NROWS = BATCH*NPTS;     // 120000
constexpr int RM    = 48;             // rows per block (2500 blocks; 52KB LDS -> 3 blocks/CU)

// scaling: A-words x 2^11, B-words x 2^14, accumulator scale 2^25
#define ASC   2048.0f
#define AINV  (1.0f/2048.0f)
#define OINV  (1.0f/33554432.0f)
#define BSC   16384.0f

typedef _Float16 f16x8 __attribute__((ext_vector_type(8)));
typedef float    f32x4 __attribute__((ext_vector_type(4)));

__device__ __forceinline__ float elu_f(float x){ return x > 0.f ? x : (__expf(x) - 1.0f); }

// split scaled value vs into hi/lo f16 bit-patterns (lo = exact residual, same scale)
__device__ __forceinline__ void split_f16(float vs, uint32_t& hb, uint32_t& lb){
    const _Float16 h = (_Float16)vs;
    const _Float16 l = (_Float16)(vs - (float)h);
    union { _Float16 f; uint16_t u; } uh, ul;
    uh.f = h; ul.f = l;
    hb = uh.u; lb = ul.u;
}
// pack activation: scale by 2^11, split, pack hi(low16)|lo(high16)
__device__ __forceinline__ uint32_t pack_act(float v){
    uint32_t hb, lb;
    split_f16(v * ASC, hb, lb);
    return hb | (lb << 16);
}
__device__ __forceinline__ float unpack_act(uint32_t u){
    union { uint16_t u16; _Float16 f; } a, b;
    a.u16 = (uint16_t)(u & 0xffffu);
    b.u16 = (uint16_t)(u >> 16);
    return ((float)a.f + (float)b.f) * AINV;
}

// prepack byte offsets: lay0 = 3 ksteps, lay1..6 = 8 ksteps; per (kstep,n16): hi 1KB + lo 1KB
__host__ __device__ __forceinline__ size_t wp_off(int lay){
    return (lay == 0) ? 0 : (size_t)(98304 + (lay-1)*262144);
}

// -------- prepack weights into MFMA B-fragment order, scaled split-f16 hi/lo --------
__global__ void prepack_kernel(const float* __restrict__ Win,
                               const float* __restrict__ Wlay,
                               unsigned char* __restrict__ wp)
{
    const int tid = blockIdx.x*256 + threadIdx.x;
    if (tid >= 7*8*16*64) return;
    const int lane  = tid & 63;
    const int n16   = (tid >> 6) & 15;
    const int kstep = (tid >> 10) & 7;
    const int lay   = tid >> 13;
    if (lay == 0 && kstep >= 3) return;
    const int kbase = 32*kstep + 8*(lane >> 4);
    const int c = 16*n16 + (lane & 15);
    uint32_t hw[4], lw[4];
    #pragma unroll
    for (int p = 0; p < 4; ++p) {
        uint32_t hh0=0, hh1=0, ll0=0, ll1=0;
        #pragma unroll
        for (int q = 0; q < 2; ++q) {
            const int k = kbase + 2*p + q;
            float w = 0.f;
            if (lay == 0) { if (k < 76) w = Win[k*HDIM + c]; }
            else w = Wlay[(size_t)(lay-1)*HDIM*HDIM + (size_t)k*HDIM + c];
            uint32_t hb, lb;
            split_f16(w * BSC, hb, lb);
            if (q == 0) { hh0 = hb; ll0 = lb; } else { hh1 = hb; ll1 = lb; }
        }
        hw[p] = hh0 | (hh1 << 16);
        lw[p] = ll0 | (ll1 << 16);
    }
    uint4* dst = (uint4*)(wp + wp_off(lay)) + (size_t)((kstep*16 + n16)*2)*64 + lane;
    dst[0]  = make_uint4(hw[0], hw[1], hw[2], hw[3]);   // hi slot
    dst[64] = make_uint4(lw[0], lw[1], lw[2], lw[3]);   // lo slot (+1KB)
}

// -------------------- fused MLP on matrix cores (scaled split-f16, 3 MFMA) --------------------
// 8 waves: each wave owns 2 n16-groups (32 cols) x all 48 rows.  [r12 proven core - FROZEN]
// Head parallelized 4 threads/row; scatter fused into the head (replaces scatter_kernel).
__launch_bounds__(512, 4)
__global__ void mlp_fused(const float* __restrict__ pos,
                          const float* __restrict__ zlat,
                          const unsigned char* __restrict__ wp,
                          const float* __restrict__ Wout1,
                          const float* __restrict__ Wout2,
                          const float* __restrict__ orient,
                          const float* __restrict__ amp,
                          const float* __restrict__ ampvar,
                          float* __restrict__ out_fp,
                          float* __restrict__ out_disp,
                          float* __restrict__ img)
{
    __shared__ uint4 h4[RM*64];      // 48 KB: packed hi/lo activations, XOR-swizzled
    __shared__ float w1s[HDIM*3];
    uint32_t* hs = (uint32_t*)h4;
    const int t = threadIdx.x;
    const int lane = t & 63;
    const int wv = t >> 6;           // 0..7
    const int row0 = blockIdx.x * RM;
    const int g  = lane >> 4;
    const int rb = lane & 15;

    // feat: 48 rows x 96 cols (60 posenc + 16 z + 20 zero pad); 48*96 = 4608 = 9*512
    for (int idx = t; idx < RM*96; idx += 512) {
        const int r = idx / 96, c = idx - r*96;
        const int row = row0 + r;
        const int b = row / NPTS, n = row - b*NPTS;
        float v = 0.f;
        if (c < 60) {
            const int d = c / 20, rem = c - d*20;
            const int f = (rem < 10) ? rem : rem - 10;
            const float ang = pos[n*3+d] * (float)(1<<f) * PI_F;
            v = (rem < 10) ? sinf(ang) : cosf(ang);
        } else if (c < 76) {
            v = zlat[b*NLAT + (c - 60)];
        }
        hs[r*256 + (c ^ ((r&7)<<2))] = pack_act(v);
    }
    for (int idx = t; idx < HDIM*3; idx += 512) w1s[idx] = Wout1[idx];
    __syncthreads();

    for (int lay = 0; lay < 7; ++lay) {
        const int KS = lay ? 8 : 3;
        const uint4* bp = (const uint4*)(wp + wp_off(lay));

        f32x4 acc[6];
        #pragma unroll
        for (int i = 0; i < 6; ++i) { f32x4 zz = {0.f,0.f,0.f,0.f}; acc[i] = zz; }

        uint4 BH0[2], BL0[2], BH1[2], BL1[2];

        auto LOADB = [&](uint4 (&H)[2], uint4 (&L)[2], int k){
            #pragma unroll
            for (int f = 0; f < 2; ++f) {
                const size_t s0 = (size_t)((k*16 + 2*wv + f)*2)*64 + lane;
                H[f] = bp[s0];
                L[f] = bp[s0 + 64];
            }
        };
        auto STEP = [&](const uint4 (&H)[2], const uint4 (&L)[2], int k){
            #pragma unroll
            for (int m = 0; m < 3; ++m) {
                const int r = 16*m + rb;
                const int s = r & 7;
                const int G0 = 8*k + 2*g;
                const uint4 p0 = h4[r*64 + (G0 ^ s)];
                const uint4 p1 = h4[r*64 + ((G0+1) ^ s)];
                const uint32_t e0=p0.x, e1=p0.y, e2=p0.z, e3=p0.w;
                const uint32_t e4=p1.x, e5=p1.y, e6=p1.z, e7=p1.w;
                union { uint4 q; f16x8 v; } ah, al;
                ah.q = make_uint4((e0 & 0xffffu) | (e1 << 16),
                                  (e2 & 0xffffu) | (e3 << 16),
                                  (e4 & 0xffffu) | (e5 << 16),
                                  (e6 & 0xffffu) | (e7 << 16));
                al.q = make_uint4((e0 >> 16) | (e1 & 0xffff0000u),
                                  (e2 >> 16) | (e3 & 0xffff0000u),
                                  (e4 >> 16) | (e5 & 0xffff0000u),
                                  (e6 >> 16) | (e7 & 0xffff0000u));
                #pragma unroll
                for (int nn = 0; nn < 2; ++nn) {
                    union { uint4 q; f16x8 v; } bh, bl;
                    bh.q = H[nn]; bl.q = L[nn];
                    f32x4 a = acc[m*2+nn];
                    a = __builtin_amdgcn_mfma_f32_16x16x32_f16(ah.v, bl.v, a, 0, 0, 0);
                    a = __builtin_amdgcn_mfma_f32_16x16x32_f16(al.v, bh.v, a, 0, 0, 0);
                    a = __builtin_amdgcn_mfma_f32_16x16x32_f16(ah.v, bh.v, a, 0, 0, 0);
                    acc[m*2+nn] = a;
                }
            }
        };

        LOADB(BH0, BL0, 0);
        for (int k = 0; k < KS; k += 2) {
            if (k+1 < KS) LOADB(BH1, BL1, k+1);
            STEP(BH0, BL0, k);
            if (k+1 < KS) {
                if (k+2 < KS) LOADB(BH0, BL0, k+2);
                STEP(BH1, BL1, k+1);
            }
        }

        __syncthreads();   // all h reads of this layer done
        const bool do_elu = (lay >= 1);
        #pragma unroll
        for (int m = 0; m < 3; ++m) {
            #pragma unroll
            for (int nn = 0; nn < 2; ++nn) {
                #pragma unroll
                for (int j = 0; j < 4; ++j) {
                    float v = acc[m*2+nn][j] * OINV;       // descale 2^-25
                    if (do_elu) v = elu_f(v);
                    const int r = 16*m + 4*g + j;          // C/D: row = 4*(lane>>4)+reg
                    const int c = 32*wv + 16*nn + rb;      // C/D: col = lane&15
                    hs[r*256 + (c ^ ((r&7)<<2))] = pack_act(v);
                }
            }
        }
        __syncthreads();
    }

    // ---- head: 256->3 (elu) -> 3x3, rotate, project, SCATTER; 4 threads per row ----
    {
        const int r = t >> 2;          // 0..127 (only r<RM active)
        const int q = t & 3;           // k-quarter
        if (r < RM) {
            const int s = (r & 7) << 2;
            const uint32_t* hr = hs + r*256;
            float o0=0.f, o1=0.f, o2=0.f;
            #pragma unroll 8
            for (int kk = 0; kk < 64; ++kk) {
                const int k = 64*q + kk;
                const float hv = unpack_act(hr[k ^ s]);
                o0 = fmaf(hv, w1s[k*3+0], o0);
                o1 = fmaf(hv, w1s[k*3+1], o1);
                o2 = fmaf(hv, w1s[k*3+2], o2);
            }
            o0 += __shfl_xor(o0, 1); o0 += __shfl_xor(o0, 2);
            o1 += __shfl_xor(o1, 1); o1 += __shfl_xor(o1, 2);
            o2 += __shfl_xor(o2, 1); o2 += __shfl_xor(o2, 2);
            if (q == 0) {
                const int row = row0 + r;
                const int b = row / NPTS, n = row - b*NPTS;
                o0 = elu_f(o0); o1 = elu_f(o1); o2 = elu_f(o2);
                const float d0 = o0*Wout2[0] + o1*Wout2[3] + o2*Wout2[6];
                const float d1 = o0*Wout2[1] + o1*Wout2[4] + o2*Wout2[7];
                const float d2 = o0*Wout2[2] + o1*Wout2[5] + o2*Wout2[8];
                const float p0 = pos[n*3+0] + d0;
                const float p1 = pos[n*3+1] + d1;
                const float p2 = pos[n*3+2] + d2;
                out_disp[(size_t)row*3+0] = d0; out_disp[(size_t)row*3+1] = d1; out_disp[(size_t)row*3+2] = d2;
                out_fp[(size_t)row*3+0]   = p0; out_fp[(size_t)row*3+1]   = p1; out_fp[(size_t)row*3+2]   = p2;
                float sa,ca,sb,cb,sc,cc;
                sincosf(orient[b*3+0], &sa, &ca);
                sincosf(orient[b*3+1], &sb, &cb);
                sincosf(orient[b*3+2], &sc, &cc);
                const float R00 =  ca*cb*cc - sa*sc;
                const float R10 =  sa*cb*cc + ca*sc;
                const float R20 = -sb*cc;
                const float R01 = -ca*cb*sc - sa*cc;
                const float R11 = -sa*cb*sc + ca*cc;
                const float R21 =  sb*sc;
                const float prx = p0*R00 + p1*R10 + p2*R20;
                const float pry = p0*R01 + p1*R11 + p2*R21;

                // fused bilinear scatter with per-point class softmax (same math as scatter_kernel)
                float x = (prx + 0.5f) * (float)(GRIDN-1);
                float y = (pry + 0.5f) * (float)(GRIDN-1);
                x = fminf(fmaxf(x, 0.f), 511.0f);
                y = fminf(fmaxf(y, 0.f), 511.0f);
                const float x0f = floorf(x), y0f = floorf(y);
                const float fx = x - x0f, fy = y - y0f;
                const int x0 = (int)x0f, y0 = (int)y0f;
                const int x1 = min(x0+1, GRIDN-1), y1 = min(y0+1, GRIDN-1);
                const float av0 = ampvar[n], av1 = ampvar[NPTS + n];
                const float mx = fmaxf(av0, av1);
                const float e0 = __expf(av0 - mx), e1 = __expf(av1 - mx);
                const float inv = 1.0f / (e0 + e1);
                const float w0 = amp[n]        * e0 * inv;
                const float w1 = amp[NPTS + n] * e1 * inv;
                const float w00 = (1.f-fx)*(1.f-fy), w10 = fx*(1.f-fy), w01 = (1.f-fx)*fy, w11 = fx*fy;
                float* img0 = img + (size_t)(b*NCLS + 0)*GRIDN*GRIDN;
                float* img1 = img + (size_t)(b*NCLS + 1)*GRIDN*GRIDN;
                const int i00 = y0*GRIDN + x0, i10 = y0*GRIDN + x1;
                const int i01 = y1*GRIDN + x0, i11 = y1*GRIDN + x1;
                atomicAdd(img0 + i00, w0*w00); atomicAdd(img0 + i10, w0*w10);
                atomicAdd(img0 + i01, w0*w01); atomicAdd(img0 + i11, w0*w11);
                atomicAdd(img1 + i00, w1*w00); atomicAdd(img1 + i10, w1*w10);
                atomicAdd(img1 + i01, w1*w01); atomicAdd(img1 + i11, w1*w11);
            }
        }
    }
}

// ---- row-pass FFT512 packing the two REAL class images as re/im of one complex FFT ----
__global__ void fft_row_pair(const float* __restrict__ img, float2* __restrict__ Z)
{
    __shared__ float2 s[512];
    const int t  = threadIdx.x;           // 256
    const int rb = blockIdx.x;            // b*512 + y
    const int b  = rb >> 9, y = rb & 511;
    const float* p0 = img + ((size_t)(b*2+0) << 18) + (size_t)y*512;
    const float* p1 = img + ((size_t)(b*2+1) << 18) + (size_t)y*512;
    #pragma unroll
    for (int j = 0; j < 2; ++j) {
        const int i  = t + j*256;
        const int ri = (int)(__brev((unsigned)i) >> 23);
        s[ri] = make_float2(p0[i], p1[i]);
    }
    for (int len = 1; len < 512; len <<= 1) {
        __syncthreads();
        const int p  = t & (len-1);
        const int i0 = ((t & ~(len-1)) << 1) | p;
        const float ang = -PI_F * (float)p / (float)len;
        float sn, cs; __sincosf(ang, &sn, &cs);
        const float2 a  = s[i0];
        const float2 bv = s[i0 + len];
        const float2 bt = make_float2(bv.x*cs - bv.y*sn, bv.x*sn + bv.y*cs);
        s[i0]       = make_float2(a.x + bt.x, a.y + bt.y);
        s[i0 + len] = make_float2(a.x - bt.x, a.y - bt.y);
    }
    __syncthreads();
    float2* zo = Z + ((size_t)b << 18) + (size_t)y*512;
    #pragma unroll
    for (int j = 0; j < 2; ++j) {
        const int i = t + j*256;
        zo[i] = s[i];
    }
}

// ---------------- generic 1-row-per-block radix-2 FFT pass ----------------
template<int N, bool INV, bool RIN, bool ROUT>
__global__ void fft_pass(const float* __restrict__ in, float* __restrict__ out,
                         int in_per, long in_s1, long in_s2, long in_es,
                         int out_per, long out_s1, long out_s2, long out_es,
                         float scale)
{
    __shared__ float2 s[N];
    const int t  = threadIdx.x;            // N/2 threads
    const int rb = blockIdx.x;
    const long ib = (long)(rb / in_per) * in_s1 + (long)(rb % in_per) * in_s2;
    constexpr int LOG2N = (N == 512) ? 9 : 8;
    #pragma unroll
    for (int j = 0; j < 2; ++j) {
        const int i  = t + j*(N/2);
        const int ri = (int)(__brev((unsigned)i) >> (32 - LOG2N));
        float2 v;
        if (RIN) { v.x = in[ib + (long)i*in_es]; v.y = 0.f; }
        else       v = ((const float2*)in)[ib + (long)i*in_es];
        s[ri] = v;
    }
    for (int len = 1; len < N; len <<= 1) {
        __syncthreads();
        const int p  = t & (len-1);
        const int i0 = ((t & ~(len-1)) << 1) | p;
        const float ang = (INV ? PI_F : -PI_F) * (float)p / (float)len;
        float sn, cs; __sincosf(ang, &sn, &cs);   // |ang| <= pi: HW fast path is safe
        const float2 a  = s[i0];
        const float2 bv = s[i0 + len];
        const float2 bt = make_float2(bv.x*cs - bv.y*sn, bv.x*sn + bv.y*cs);
        s[i0]       = make_float2(a.x + bt.x, a.y + bt.y);
        s[i0 + len] = make_float2(a.x - bt.x, a.y - bt.y);
    }
    __syncthreads();
    const long ob = (long)(rb / out_per) * out_s1 + (long)(rb % out_per) * out_s2;
    #pragma unroll
    for (int j = 0; j < 2; ++j) {
        const int i = t + j*(N/2);
        if (ROUT) out[ob + (long)i*out_es] = s[i].x * scale;
        else {
            float2 v = s[i]; v.x *= scale; v.y *= scale;
            ((float2*)out)[ob + (long)i*out_es] = v;
        }
    }
}

// -------- unpack packed real-pair spectrum + filter + class-sum + crop + Herm + shift --------
// Z = FFT2(img_c0 + i*img_c1) per batch.  F0(k) = (Z(k)+conj(Z(-k)))/2,
// F1(k) = -i(Z(k)-conj(Z(-k)))/2.  Crop-mirror positions handled with explicit indices.
__global__ void combine_kernel(const float2* __restrict__ Z,
                               const float* __restrict__ Afac,
                               const float* __restrict__ Bw,
                               const float* __restrict__ shift,
                               float2* __restrict__ Q)
{
    const int u = blockIdx.x;
    const int b = blockIdx.y;
    const int v = threadIdx.x;
    const int mu  = (u < 128) ? u : u + 256;
    const int mv  = (v < 128) ? v : v + 256;
    const int u2  = (256 - u) & 255;
    const int v2  = (256 - v) & 255;
    const int mu2 = (u2 < 128) ? u2 : u2 + 256;
    const int mv2 = (v2 < 128) ? v2 : v2 + 256;
    const int nmu  = (512 - mu)  & 511;
    const int nmv  = (512 - mv)  & 511;
    const int nmu2 = (512 - mu2) & 511;
    const int nmv2 = (512 - mv2) & 511;

    const float2* Zb = Z + ((size_t)b << 18);
    const float2 A   = Zb[(size_t)mu  *512 + mv ];
    const float2 Am  = Zb[(size_t)nmu *512 + nmv];
    const float2 A2  = Zb[(size_t)mu2 *512 + mv2];
    const float2 A2m = Zb[(size_t)nmu2*512 + nmv2];

    float2 F1v[2], FHv[2];
    F1v[0] = make_float2(0.5f*(A.x + Am.x),  0.5f*(A.y - Am.y));     // F0(k)
    F1v[1] = make_float2(0.5f*(A.y + Am.y), -0.5f*(A.x - Am.x));     // F1(k)
    FHv[0] = make_float2(0.5f*(A2.x + A2m.x),  0.5f*(A2.y - A2m.y)); // F0(crop-mirror)
    FHv[1] = make_float2(0.5f*(A2.y + A2m.y), -0.5f*(A2.x - A2m.x)); // F1(crop-mirror)

    const float fy1 = (float)((mu  < 256) ? mu  : mu  - 512) / 512.0f;
    const float fx1 = (float)((mv  < 256) ? mv  : mv  - 512) / 512.0f;
    const float fy2 = (float)((mu2 < 256) ? mu2 : mu2 - 512) / 512.0f;
    const float fx2 = (float)((mv2 < 256) ? mv2 : mv2 - 512) / 512.0f;
    const float R1 = fy1*fy1 + fx1*fx1;
    const float R2 = fy2*fy2 + fx2*fx2;
    float a1x=0.f, a1y=0.f, a2x=0.f, a2y=0.f;
    #pragma unroll
    for (int c = 0; c < NCLS; ++c) {
        const float bw = Bw[c];
        const float f1 = Afac[c] * __expf(-bw*bw*R1);
        const float f2 = Afac[c] * __expf(-bw*bw*R2);
        a1x = fmaf(f1, F1v[c].x, a1x); a1y = fmaf(f1, F1v[c].y, a1y);
        a2x = fmaf(f2, FHv[c].x, a2x); a2y = fmaf(f2, FHv[c].y, a2y);
    }
    const float Gx = 0.5f*(a1x + a2x);
    const float Gy = 0.5f*(a1y - a2y);
    const float fu = (float)((u < 128) ? u : u - 256) / 256.0f;
    const float fv = (float)((v < 128) ? v : v - 256) / 256.0f;
    const float th = -2.0f*PI_F*(shift[b*2+0]*fv + shift[b*2+1]*fu);
    float sn, cs; __sincosf(th, &sn, &cs);
    float2 o;
    o.x = Gx*cs - Gy*sn;
    o.y = Gx*sn + Gy*cs;
    Q[((size_t)b << 16) + (size_t)u*256 + v] = o;
}

extern "C" void kernel_launch(void* const* d_in, const int* in_sizes, int n_in,
                              void* d_out, int out_size, void* d_ws, size_t ws_size,
                              hipStream_t stream)
{
    (void)in_sizes; (void)n_in; (void)out_size; (void)ws_size;
    const float* z      = (const float*)d_in[0];
    const float* orient = (const float*)d_in[1];
    const float* shift  = (const float*)d_in[2];
    const float* pos    = (const float*)d_in[3];
    const float* amp    = (const float*)d_in[4];
    const float* ampvar = (const float*)d_in[5];
    const float* Win    = (const float*)d_in[6];
    const float* Wlay   = (const float*)d_in[7];
    const float* Wout1  = (const float*)d_in[8];
    const float* Wout2  = (const float*)d_in[9];
    const float* Afac   = (const float*)d_in[10];
    const float* Bw     = (const float*)d_in[11];

    float* out      = (float*)d_out;
    float* out_img  = out;
    float* out_fp   = out + (size_t)BATCH*BOXN*BOXN;
    float* out_disp = out_fp + (size_t)NROWS*3;

    char*   ws   = (char*)d_ws;
    float*  img  = (float*)ws;                               // 8 MB: [b][c][512][512] real
    float2* Zb   = (float2*)(ws + (size_t)8*1024*1024);      // 8 MB: [b][512][512] complex (packed pair)
    unsigned char* wp = (unsigned char*)(ws + (size_t)8*1024*1024);  // 1.63 MB, dead after mlp (Z written later)
    float2* Q    = (float2*)(ws + (size_t)25165824);         // 2 MB

    (void)hipMemsetAsync(img, 0, (size_t)BATCH*NCLS*GRIDN*GRIDN*sizeof(float), stream);

    prepack_kernel<<<(7*8*16*64 + 255)/256, 256, 0, stream>>>(Win, Wlay, wp);

    mlp_fused<<<NROWS/RM, 512, 0, stream>>>(pos, z, wp, Wout1, Wout2, orient,
                                            amp, ampvar, out_fp, out_disp, img);

    // packed forward FFT2: rows (real pair -> complex), then columns (in place)
    fft_row_pair<<<BATCH*512, 256, 0, stream>>>(img, Zb);
    fft_pass<512,false,false,false><<<BATCH*512, 256, 0, stream>>>(
        (const float*)Zb, (float*)Zb, 512, 262144, 1, 512, 512, 262144, 1, 512, 1.0f);

    combine_kernel<<<dim3(256, BATCH), 256, 0, stream>>>(Zb, Afac, Bw, shift, Q);

    fft_pass<256,true ,false,false><<<BATCH*256, 128, 0, stream>>>(
        (const float*)Q, (float*)Q, 256, 65536, 256, 1, 256, 65536, 256, 1, 1.0f/256.0f);
    fft_pass<256,true ,false,true ><<<BATCH*256, 128, 0, stream>>>(
        (const float*)Q, out_img, 256, 65536, 1, 256, 256, 65536, 1, 256, 0.25f/256.0f);
}